// Round 1
// baseline (10511.629 us; speedup 1.0000x reference)
//
#include <hip/hip_runtime.h>
#include <hip/hip_bf16.h>
#include <math.h>

// Problem constants (BertCrf)
#define NB   16      // batch
#define SS   128     // seq len
#define HH   768     // hidden
#define NHD  12      // heads
#define DHD  64      // head dim
#define FFD  3072    // ffn dim
#define NLAY 12      // layers
#define NT   9       // tags
#define TOK  (NB*SS) // 2048 tokens

__device__ __forceinline__ float wave_sum(float v) {
#pragma unroll
    for (int o = 32; o > 0; o >>= 1) v += __shfl_down(v, o, 64);
    return v;
}

// ---------------- embedding + LN ----------------
__global__ __launch_bounds__(256) void embed_ln_k(
    const int* __restrict__ ids, const int* __restrict__ tt,
    const float* __restrict__ we, const float* __restrict__ pe,
    const float* __restrict__ te, const float* __restrict__ g,
    const float* __restrict__ bb, float* __restrict__ out)
{
    int tok = blockIdx.x;
    int s = tok % SS;
    int id = ids[tok];
    int ty = tt[tok];
    const float* wr = we + (size_t)id * HH;
    const float* pr = pe + (size_t)s * HH;
    const float* tr = te + (size_t)ty * HH;

    float x[3];
    float sum = 0.f;
#pragma unroll
    for (int i = 0; i < 3; i++) {
        int c = threadIdx.x + i * 256;
        float v = wr[c] + pr[c] + tr[c];
        x[i] = v; sum += v;
    }
    __shared__ float red[4];
    int lane = threadIdx.x & 63, wid = threadIdx.x >> 6;
    float t1 = wave_sum(sum);
    if (lane == 0) red[wid] = t1;
    __syncthreads();
    float mean = (red[0] + red[1] + red[2] + red[3]) * (1.0f / HH);
    __syncthreads();
    float sq = 0.f;
#pragma unroll
    for (int i = 0; i < 3; i++) { x[i] -= mean; sq += x[i] * x[i]; }
    float t2 = wave_sum(sq);
    if (lane == 0) red[wid] = t2;
    __syncthreads();
    float var = (red[0] + red[1] + red[2] + red[3]) * (1.0f / HH);
    float inv = rsqrtf(var + 1e-12f);
    float* o = out + (size_t)tok * HH;
#pragma unroll
    for (int i = 0; i < 3; i++) {
        int c = threadIdx.x + i * 256;
        o[c] = g[c] * x[i] * inv + bb[c];
    }
}

// ---------------- residual add + LN (in place on h) ----------------
__global__ __launch_bounds__(256) void resln_k(
    float* __restrict__ h, const float* __restrict__ p,
    const float* __restrict__ g, const float* __restrict__ bb)
{
    int tok = blockIdx.x;
    float* hr = h + (size_t)tok * HH;
    const float* pr = p + (size_t)tok * HH;
    float x[3];
    float sum = 0.f;
#pragma unroll
    for (int i = 0; i < 3; i++) {
        int c = threadIdx.x + i * 256;
        float v = hr[c] + pr[c];
        x[i] = v; sum += v;
    }
    __shared__ float red[4];
    int lane = threadIdx.x & 63, wid = threadIdx.x >> 6;
    float t1 = wave_sum(sum);
    if (lane == 0) red[wid] = t1;
    __syncthreads();
    float mean = (red[0] + red[1] + red[2] + red[3]) * (1.0f / HH);
    __syncthreads();
    float sq = 0.f;
#pragma unroll
    for (int i = 0; i < 3; i++) { x[i] -= mean; sq += x[i] * x[i]; }
    float t2 = wave_sum(sq);
    if (lane == 0) red[wid] = t2;
    __syncthreads();
    float var = (red[0] + red[1] + red[2] + red[3]) * (1.0f / HH);
    float inv = rsqrtf(var + 1e-12f);
#pragma unroll
    for (int i = 0; i < 3; i++) {
        int c = threadIdx.x + i * 256;
        hr[c] = g[c] * x[i] * inv + bb[c];
    }
}

// ---------------- fp32 SGEMM: C = A(MxK) @ W(KxN) + bias ----------------
// 64x64 tile, BK=16, 256 threads, 4x4 microtile
__global__ __launch_bounds__(256) void sgemm_k(
    const float* __restrict__ A, const float* __restrict__ W,
    const float* __restrict__ bias, float* __restrict__ C,
    int M, int N, int K)
{
    __shared__ float As[16][64];
    __shared__ float Bs[16][64];
    int tid = threadIdx.x;
    int tx = tid & 15, tyy = tid >> 4;
    int row0 = blockIdx.y * 64, col0 = blockIdx.x * 64;

    int arow = tid >> 2;          // 0..63
    int acol = (tid & 3) << 2;    // 0,4,8,12
    int brow = tid >> 4;          // 0..15
    int bcol = (tid & 15) << 2;   // 0..60

    const float* Ap = A + (size_t)(row0 + arow) * K + acol;
    const float* Wp = W + (size_t)brow * N + col0 + bcol;

    float acc[4][4] = {};
    for (int k0 = 0; k0 < K; k0 += 16) {
        float4 av = *(const float4*)(Ap + k0);
        float4 bv = *(const float4*)(Wp + (size_t)k0 * N);
        As[acol + 0][arow] = av.x;
        As[acol + 1][arow] = av.y;
        As[acol + 2][arow] = av.z;
        As[acol + 3][arow] = av.w;
        *(float4*)&Bs[brow][bcol] = bv;
        __syncthreads();
#pragma unroll
        for (int k = 0; k < 16; k++) {
            float4 a = *(const float4*)&As[k][tyy << 2];
            float4 b = *(const float4*)&Bs[k][tx << 2];
            acc[0][0] += a.x * b.x; acc[0][1] += a.x * b.y; acc[0][2] += a.x * b.z; acc[0][3] += a.x * b.w;
            acc[1][0] += a.y * b.x; acc[1][1] += a.y * b.y; acc[1][2] += a.y * b.z; acc[1][3] += a.y * b.w;
            acc[2][0] += a.z * b.x; acc[2][1] += a.z * b.y; acc[2][2] += a.z * b.z; acc[2][3] += a.z * b.w;
            acc[3][0] += a.w * b.x; acc[3][1] += a.w * b.y; acc[3][2] += a.w * b.z; acc[3][3] += a.w * b.w;
        }
        __syncthreads();
    }
    float4 bsv = *(const float4*)&bias[col0 + (tx << 2)];
#pragma unroll
    for (int i = 0; i < 4; i++) {
        int r = row0 + (tyy << 2) + i;
        float4 o;
        o.x = acc[i][0] + bsv.x;
        o.y = acc[i][1] + bsv.y;
        o.z = acc[i][2] + bsv.z;
        o.w = acc[i][3] + bsv.w;
        *(float4*)&C[(size_t)r * N + col0 + (tx << 2)] = o;
    }
}

// ---------------- attention scores: Sc[b,h,q,k] = Q.K/8 + bias ----------------
__global__ __launch_bounds__(256) void attn_scores_k(
    const float* __restrict__ Qb, const float* __restrict__ Kb,
    const int* __restrict__ mask, float* __restrict__ Sc)
{
    int bh = blockIdx.x;
    int b = bh / NHD, hh = bh % NHD;
    __shared__ float Ks[SS][DHD + 1];
    for (int i = threadIdx.x; i < SS * DHD; i += 256) {
        int k = i >> 6, d = i & 63;
        Ks[k][d] = Kb[(size_t)(b * SS + k) * HH + hh * DHD + d];
    }
    __syncthreads();
    int kk = threadIdx.x & 127;
    int qh = threadIdx.x >> 7;  // 0..1
    float biasv = (1.0f - (float)mask[b * SS + kk]) * -1e9f;
    for (int q = qh; q < SS; q += 2) {
        const float* Qr = Qb + (size_t)(b * SS + q) * HH + hh * DHD;
        float acc = 0.f;
#pragma unroll 8
        for (int d = 0; d < DHD; d++) acc += Qr[d] * Ks[kk][d];
        Sc[((size_t)bh * SS + q) * SS + kk] = acc * 0.125f + biasv;
    }
}

// ---------------- row softmax over 128 (one wave per row) ----------------
__global__ __launch_bounds__(64) void softmax_k(float* __restrict__ Sc)
{
    size_t row = blockIdx.x;
    float* p = Sc + row * SS;
    int t = threadIdx.x;
    float a = p[t], b = p[t + 64];
    float mx = fmaxf(a, b);
#pragma unroll
    for (int o = 32; o > 0; o >>= 1) mx = fmaxf(mx, __shfl_down(mx, o, 64));
    mx = __shfl(mx, 0, 64);
    float ea = expf(a - mx), eb = expf(b - mx);
    float sm = ea + eb;
#pragma unroll
    for (int o = 32; o > 0; o >>= 1) sm += __shfl_down(sm, o, 64);
    sm = __shfl(sm, 0, 64);
    float inv = 1.0f / sm;
    p[t] = ea * inv;
    p[t + 64] = eb * inv;
}

// ---------------- ctx[b,q,h,d] = sum_k P[b,h,q,k] V[b,k,h,d] ----------------
__global__ __launch_bounds__(256) void attn_ctx_k(
    const float* __restrict__ Sc, const float* __restrict__ Vb,
    float* __restrict__ Cb)
{
    int bh = blockIdx.x;
    int b = bh / NHD, hh = bh % NHD;
    __shared__ float Vs[SS][DHD];   // stride 64: 2-way bank alias = free
    for (int i = threadIdx.x; i < SS * DHD; i += 256) {
        int k = i >> 6, d = i & 63;
        Vs[k][d] = Vb[(size_t)(b * SS + k) * HH + hh * DHD + d];
    }
    __syncthreads();
    int d = threadIdx.x & 63;
    int qg = threadIdx.x >> 6;  // 0..3
    for (int q = qg; q < SS; q += 4) {
        const float* P = Sc + ((size_t)bh * SS + q) * SS;
        float acc = 0.f;
#pragma unroll 8
        for (int k = 0; k < SS; k++) acc += P[k] * Vs[k][d];
        Cb[(size_t)(b * SS + q) * HH + hh * DHD + d] = acc;
    }
}

// ---------------- exact GELU ----------------
__global__ __launch_bounds__(256) void gelu_k(float* __restrict__ x, int n4)
{
    int i = blockIdx.x * 256 + threadIdx.x;
    if (i < n4) {
        float4 v = ((float4*)x)[i];
        v.x = 0.5f * v.x * (1.f + erff(v.x * 0.70710678118654752f));
        v.y = 0.5f * v.y * (1.f + erff(v.y * 0.70710678118654752f));
        v.z = 0.5f * v.z * (1.f + erff(v.z * 0.70710678118654752f));
        v.w = 0.5f * v.w * (1.f + erff(v.w * 0.70710678118654752f));
        ((float4*)x)[i] = v;
    }
}

// ---------------- emissions: em = h @ fc_w + fc_b  (N=9) ----------------
__global__ __launch_bounds__(64) void emissions_k(
    const float* __restrict__ h, const float* __restrict__ fcw,
    const float* __restrict__ fcb, float* __restrict__ em)
{
    int tok = blockIdx.x;
    const float* hr = h + (size_t)tok * HH;
    float acc[NT];
#pragma unroll
    for (int t = 0; t < NT; t++) acc[t] = 0.f;
    for (int c = threadIdx.x; c < HH; c += 64) {
        float x = hr[c];
#pragma unroll
        for (int t = 0; t < NT; t++) acc[t] += x * fcw[c * NT + t];
    }
#pragma unroll
    for (int t = 0; t < NT; t++) {
        float v = wave_sum(acc[t]);
        if (threadIdx.x == 0) em[(size_t)tok * NT + t] = v + fcb[t];
    }
}

// ---------------- CRF forward (one block per batch element) ----------------
__global__ __launch_bounds__(64) void crf_k(
    const float* __restrict__ em, const int* __restrict__ tags,
    const int* __restrict__ mask, const float* __restrict__ startv,
    const float* __restrict__ endv, const float* __restrict__ trans,
    float* __restrict__ llh)
{
    int b = blockIdx.x;
    const float* E = em + (size_t)b * SS * NT;
    __shared__ float alpha[NT];
    __shared__ float nalpha[NT];
    int j = threadIdx.x;
    if (j < NT) alpha[j] = startv[j] + E[j];
    __syncthreads();
    for (int t = 1; t < SS; t++) {
        if (j < NT) {
            int m = mask[b * SS + t];
            float mx = -1e30f;
#pragma unroll
            for (int i = 0; i < NT; i++) mx = fmaxf(mx, alpha[i] + trans[i * NT + j]);
            float sm = 0.f;
#pragma unroll
            for (int i = 0; i < NT; i++) sm += expf(alpha[i] + trans[i * NT + j] - mx);
            float nx = mx + logf(sm) + E[t * NT + j];
            nalpha[j] = m ? nx : alpha[j];
        }
        __syncthreads();
        if (j < NT) alpha[j] = nalpha[j];
        __syncthreads();
    }
    if (j == 0) {
        float mx = -1e30f;
        for (int i = 0; i < NT; i++) mx = fmaxf(mx, alpha[i] + endv[i]);
        float sm = 0.f;
        for (int i = 0; i < NT; i++) sm += expf(alpha[i] + endv[i] - mx);
        float logZ = mx + logf(sm);

        const int* tg = tags + b * SS;
        float num = startv[tg[0]] + E[tg[0]];
        for (int t = 1; t < SS; t++) {
            float msk = (float)mask[b * SS + t];
            num += (trans[tg[t - 1] * NT + tg[t]] + E[t * NT + tg[t]]) * msk;
        }
        int cnt = 0;
        for (int t = 0; t < SS; t++) cnt += mask[b * SS + t];
        num += endv[tg[cnt - 1]];
        llh[b] = num - logZ;
    }
}

__global__ __launch_bounds__(64) void loss_k(const float* __restrict__ llh, float* __restrict__ out)
{
    if (threadIdx.x == 0) {
        float s = 0.f;
        for (int b = 0; b < NB; b++) s += llh[b];
        out[0] = -s / NB;
    }
}

extern "C" void kernel_launch(void* const* d_in, const int* in_sizes, int n_in,
                              void* d_out, int out_size, void* d_ws, size_t ws_size,
                              hipStream_t stream)
{
    const int* ids  = (const int*)d_in[0];
    const int* mask = (const int*)d_in[1];
    const int* tt   = (const int*)d_in[2];
    const int* tags = (const int*)d_in[3];
    const float* wemb = (const float*)d_in[4];
    const float* pemb = (const float*)d_in[5];
    const float* temb = (const float*)d_in[6];
    const float* elg  = (const float*)d_in[7];
    const float* elb  = (const float*)d_in[8];
    const float* Wq = (const float*)d_in[9];
    const float* bq = (const float*)d_in[10];
    const float* Wk = (const float*)d_in[11];
    const float* bk = (const float*)d_in[12];
    const float* Wv = (const float*)d_in[13];
    const float* bv = (const float*)d_in[14];
    const float* Wo = (const float*)d_in[15];
    const float* bo = (const float*)d_in[16];
    const float* g1 = (const float*)d_in[17];
    const float* b1 = (const float*)d_in[18];
    const float* Wi = (const float*)d_in[19];
    const float* bi = (const float*)d_in[20];
    const float* Wo2 = (const float*)d_in[21];
    const float* bo2 = (const float*)d_in[22];
    const float* g2 = (const float*)d_in[23];
    const float* b2 = (const float*)d_in[24];
    const float* fcw = (const float*)d_in[25];
    const float* fcb = (const float*)d_in[26];
    const float* cst = (const float*)d_in[27];
    const float* cen = (const float*)d_in[28];
    const float* ctr = (const float*)d_in[29];

    float* ws = (float*)d_ws;
    const size_t TH = (size_t)TOK * HH;
    float* h  = ws;
    float* qb = h + TH;
    float* kb = qb + TH;
    float* vb = kb + TH;
    float* ob = vb + TH;                                  // ctx / proj out
    float* sc = ob + TH;                                  // (B,NH,S,S)
    float* ff = sc + (size_t)NB * NHD * SS * SS;          // (TOK,FF)
    float* llh = ff + (size_t)TOK * FFD;

    float* emis = (float*)d_out;
    float* loss = emis + (size_t)TOK * NT;

    embed_ln_k<<<TOK, 256, 0, stream>>>(ids, tt, wemb, pemb, temb, elg, elb, h);

    for (int l = 0; l < NLAY; l++) {
        const float* wql = Wq + (size_t)l * HH * HH;  const float* bql = bq + (size_t)l * HH;
        const float* wkl = Wk + (size_t)l * HH * HH;  const float* bkl = bk + (size_t)l * HH;
        const float* wvl = Wv + (size_t)l * HH * HH;  const float* bvl = bv + (size_t)l * HH;
        const float* wol = Wo + (size_t)l * HH * HH;  const float* bol = bo + (size_t)l * HH;
        const float* g1l = g1 + (size_t)l * HH;       const float* b1l = b1 + (size_t)l * HH;
        const float* wil = Wi + (size_t)l * HH * FFD; const float* bil = bi + (size_t)l * FFD;
        const float* w2l = Wo2 + (size_t)l * FFD * HH; const float* b2l_ = bo2 + (size_t)l * HH;
        const float* g2l = g2 + (size_t)l * HH;       const float* b2l = b2 + (size_t)l * HH;

        dim3 gH(HH / 64, TOK / 64);
        dim3 gF(FFD / 64, TOK / 64);

        sgemm_k<<<gH, 256, 0, stream>>>(h, wql, bql, qb, TOK, HH, HH);
        sgemm_k<<<gH, 256, 0, stream>>>(h, wkl, bkl, kb, TOK, HH, HH);
        sgemm_k<<<gH, 256, 0, stream>>>(h, wvl, bvl, vb, TOK, HH, HH);
        attn_scores_k<<<NB * NHD, 256, 0, stream>>>(qb, kb, mask, sc);
        softmax_k<<<NB * NHD * SS, 64, 0, stream>>>(sc);
        attn_ctx_k<<<NB * NHD, 256, 0, stream>>>(sc, vb, ob);
        sgemm_k<<<gH, 256, 0, stream>>>(ob, wol, bol, qb, TOK, HH, HH);
        resln_k<<<TOK, 256, 0, stream>>>(h, qb, g1l, b1l);
        sgemm_k<<<gF, 256, 0, stream>>>(h, wil, bil, ff, TOK, FFD, HH);
        gelu_k<<<(TOK * FFD / 4 + 255) / 256, 256, 0, stream>>>(ff, TOK * FFD / 4);
        sgemm_k<<<gH, 256, 0, stream>>>(ff, w2l, b2l_, qb, TOK, HH, FFD);
        resln_k<<<TOK, 256, 0, stream>>>(h, qb, g2l, b2l);
    }

    emissions_k<<<TOK, 64, 0, stream>>>(h, fcw, fcb, emis);
    crf_k<<<NB, 64, 0, stream>>>(emis, tags, mask, cst, cen, ctr, llh);
    loss_k<<<1, 64, 0, stream>>>(llh, loss);
}